// Round 1
// baseline (591.180 us; speedup 1.0000x reference)
//
#include <hip/hip_runtime.h>

#define F 64
#define P 32
#define MAXD 10

// ---------------- degree count ----------------
__global__ void k_count_deg(const int* __restrict__ dst, int* __restrict__ deg, int E) {
  int i = blockIdx.x * blockDim.x + threadIdx.x;
  int stride = gridDim.x * blockDim.x;
  for (int e = i; e < E; e += stride) atomicAdd(&deg[dst[e]], 1);
}

// ---------------- single-block exclusive scan over deg -> off, cur, dinv ----------------
__global__ void k_scan(const int* __restrict__ deg, int* __restrict__ off, int* __restrict__ cur,
                       float* __restrict__ dinv, int N) {
  __shared__ int s[1024];
  int t = threadIdx.x;
  int chunk = (N + 1023) >> 10;
  int lo = t * chunk, hi = min(lo + chunk, N);
  int sum = 0;
  for (int n = lo; n < hi; ++n) sum += deg[n];
  s[t] = sum;
  __syncthreads();
  for (int o = 1; o < 1024; o <<= 1) {
    int v = (t >= o) ? s[t - o] : 0;
    __syncthreads();
    s[t] += v;
    __syncthreads();
  }
  int run = s[t] - sum;  // exclusive base for this chunk
  for (int n = lo; n < hi; ++n) {
    off[n] = run;
    cur[n] = run;
    dinv[n] = rsqrtf((float)(deg[n] + 1));  // +1 self loop (GCN)
    run += deg[n];
  }
  if (t == 1023) off[N] = s[1023];
}

// ---------------- CSR fill: per dst node, list of src ----------------
__global__ void k_fill(const int* __restrict__ src, const int* __restrict__ dst,
                       int* __restrict__ cur, int* __restrict__ csr, int E) {
  int i = blockIdx.x * blockDim.x + threadIdx.x;
  int stride = gridDim.x * blockDim.x;
  for (int e = i; e < E; e += stride) {
    int d = dst[e];
    int pos = atomicAdd(&cur[d], 1);
    csr[pos] = src[e];
  }
}

// ---------------- GEMM: out[n,f] = dinv[n] * sum_k X[n,k] * W[k,f] ----------------
// wave per node (grid-stride), lane f holds column f of W in registers
template <int KOUT>
__global__ void k_gemm(const float* __restrict__ X, const float* __restrict__ W,
                       const float* __restrict__ dinv, float* __restrict__ out, int N) {
  int gtid = blockIdx.x * blockDim.x + threadIdx.x;
  int wave = gtid >> 6;
  int lane = threadIdx.x & 63;
  int nwaves = (gridDim.x * blockDim.x) >> 6;
  int f = lane & (KOUT - 1);
  float w[F];
#pragma unroll
  for (int k = 0; k < F; ++k) w[k] = W[k * KOUT + f];
  for (int n = wave; n < N; n += nwaves) {
    float xv = X[(size_t)n * F + lane];
    float acc = 0.f;
#pragma unroll
    for (int k = 0; k < F; ++k) acc += __shfl(xv, k, 64) * w[k];
    if (lane < KOUT) out[(size_t)n * KOUT + lane] = acc * dinv[n];
  }
}

// ---------------- GCN aggregation: out[n] = dinv[n]*(sum_adj T[src] + T[n]) + b ----------------
// T rows are pre-scaled by dinv[src]; wave per node, lane = feature
template <int KOUT>
__global__ void k_agg(const float* __restrict__ T, const int* __restrict__ csr,
                      const int* __restrict__ off, const float* __restrict__ dinv,
                      const float* __restrict__ bias, float* __restrict__ out, int N) {
  int wave = (blockIdx.x * blockDim.x + threadIdx.x) >> 6;
  int lane = threadIdx.x & 63;
  if (wave >= N) return;
  int n = wave;
  int e0 = off[n], e1 = off[n + 1];
  float acc = (lane < KOUT) ? T[(size_t)n * KOUT + lane] : 0.f;  // self loop
  for (int e = e0; e < e1; e += 64) {
    int cnt = min(64, e1 - e);
    int se = (e + lane < e1) ? csr[e + lane] : 0;
    for (int j = 0; j < cnt; ++j) {
      int s = __shfl(se, j, 64);
      if (lane < KOUT) acc += T[(size_t)s * KOUT + lane];
    }
  }
  if (lane < KOUT) out[(size_t)n * KOUT + lane] = acc * dinv[n] + bias[lane];
}

// ---------------- MFConv fused: val[n] = dot(sum_adj H[src], Wl[dc]) + dot(H[n], Wr[dc]) + bl[dc] ----------------
__global__ void k_mf(const float* __restrict__ H, const int* __restrict__ csr,
                     const int* __restrict__ off, const float* __restrict__ Wl,
                     const float* __restrict__ bl, const float* __restrict__ Wr,
                     float* __restrict__ val, int N) {
  int wave = (blockIdx.x * blockDim.x + threadIdx.x) >> 6;
  int lane = threadIdx.x & 63;
  if (wave >= N) return;
  int n = wave;
  int e0 = off[n], e1 = off[n + 1];
  float acc = 0.f;
  for (int e = e0; e < e1; e += 64) {
    int cnt = min(64, e1 - e);
    int se = (e + lane < e1) ? csr[e + lane] : 0;
    for (int j = 0; j < cnt; ++j) {
      int s = __shfl(se, j, 64);
      acc += H[(size_t)s * F + lane];
    }
  }
  int dc = min(e1 - e0, MAXD);
  float part = acc * Wl[dc * F + lane] + H[(size_t)n * F + lane] * Wr[dc * F + lane];
#pragma unroll
  for (int o = 32; o > 0; o >>= 1) part += __shfl_xor(part, o, 64);
  if (lane == 0) val[n] = part + bl[dc];
}

// ---------------- pooling: batch is SORTED -> per-block LDS accumulate, flush touched graphs ----------------
__global__ void k_pool(const float* __restrict__ pol, const float* __restrict__ val,
                       const int* __restrict__ batch, float* __restrict__ out,
                       float* __restrict__ cntg, int N, int G) {
  __shared__ float pol_l[64 * 32];
  __shared__ float val_l[64];
  __shared__ float cnt_l[64];
  int t = threadIdx.x;
  for (int i = t; i < 64 * 32; i += 256) pol_l[i] = 0.f;
  if (t < 64) { val_l[t] = 0.f; cnt_l[t] = 0.f; }
  __syncthreads();
  int base = blockIdx.x * 256;
  int p = t & 31, sub = t >> 5;
  for (int i = sub; i < 256; i += 8) {
    int n = base + i;
    if (n >= N) break;
    int g = batch[n];
    atomicAdd(&pol_l[g * 32 + p], pol[(size_t)n * 32 + p]);
    if (p == 0) {
      atomicAdd(&val_l[g], val[n]);
      atomicAdd(&cnt_l[g], 1.f);
    }
  }
  __syncthreads();
  int last = min(base + 256, N) - 1;
  if (last < base) return;
  int gmin = batch[base], gmax = batch[last];
  int ng = gmax - gmin + 1;
  for (int idx = t; idx < ng * 32; idx += 256) {
    int g = gmin + (idx >> 5), pp = idx & 31;
    atomicAdd(&out[g * 32 + pp], pol_l[g * 32 + pp]);
    if (pp == 0) {
      atomicAdd(&out[(size_t)G * 32 + g], val_l[g]);
      atomicAdd(&cntg[g], cnt_l[g]);
    }
  }
}

// ---------------- finalize: mean for policy ----------------
__global__ void k_fin(float* __restrict__ out, const float* __restrict__ cntg, int G) {
  int i = blockIdx.x * blockDim.x + threadIdx.x;
  if (i < G * 32) out[i] /= fmaxf(cntg[i >> 5], 1.0f);
}

extern "C" void kernel_launch(void* const* d_in, const int* in_sizes, int n_in,
                              void* d_out, int out_size, void* d_ws, size_t ws_size,
                              hipStream_t stream) {
  const float* x = (const float*)d_in[0];
  const int* ei = (const int*)d_in[1];
  const int* batch = (const int*)d_in[2];
  const float* W_in = (const float*)d_in[3];
  const float* b_in = (const float*)d_in[4];
  const float* W1 = (const float*)d_in[5];
  const float* b1 = (const float*)d_in[6];
  const float* Wl = (const float*)d_in[7];
  const float* bl = (const float*)d_in[8];
  const float* Wr = (const float*)d_in[9];
  const float* W_pol = (const float*)d_in[10];
  const float* b_pol = (const float*)d_in[11];
  float* out = (float*)d_out;

  const int N = in_sizes[0] / F;
  const int E = in_sizes[1] / 2;
  const int G = out_size / (P + 1);
  const int* esrc = ei;
  const int* edst = ei + E;

  char* ws = (char*)d_ws;
  size_t o = 0;
  auto alloc = [&](size_t bytes) {
    char* r = ws + o;
    o = (o + bytes + 255) & ~(size_t)255;
    return r;
  };
  int* deg = (int*)alloc((size_t)N * 4);
  int* off = (int*)alloc((size_t)(N + 1) * 4);
  int* cur = (int*)alloc((size_t)N * 4);
  float* dinv = (float*)alloc((size_t)N * 4);
  int* csr = (int*)alloc((size_t)E * 4);
  float* cntg = (float*)alloc((size_t)G * 4);
  float* valn = (float*)alloc((size_t)N * 4);
  float* bufA = (float*)alloc((size_t)N * F * 4);
  float* bufB = (float*)alloc((size_t)N * F * 4);
  float* polbuf = bufA + (size_t)N * P;  // alias upper half of bufA (t3 lives in lower half)
  (void)ws_size; (void)n_in;

  hipMemsetAsync(deg, 0, (size_t)N * 4, stream);
  hipMemsetAsync(cntg, 0, (size_t)G * 4, stream);
  hipMemsetAsync(d_out, 0, (size_t)out_size * 4, stream);

  const int bs = 256;
  k_count_deg<<<1024, bs, 0, stream>>>(edst, deg, E);
  k_scan<<<1, 1024, 0, stream>>>(deg, off, cur, dinv, N);
  k_fill<<<1024, bs, 0, stream>>>(esrc, edst, cur, csr, E);

  int aggBlocks = (N * 64 + bs - 1) / bs;  // wave per node, 4 waves/block

  // conv_in: t1' = dinv * (x @ W_in); h1 = dinv*(sum t1' + self) + b_in
  k_gemm<F><<<2048, bs, 0, stream>>>(x, W_in, dinv, bufA, N);
  k_agg<F><<<aggBlocks, bs, 0, stream>>>(bufA, csr, off, dinv, b_in, bufB, N);
  // conv_1
  k_gemm<F><<<2048, bs, 0, stream>>>(bufB, W1, dinv, bufA, N);
  k_agg<F><<<aggBlocks, bs, 0, stream>>>(bufA, csr, off, dinv, b1, bufB, N);
  // conv_policy (GEMM first: scatter only 32 feats)
  k_gemm<P><<<2048, bs, 0, stream>>>(bufB, W_pol, dinv, bufA, N);
  k_agg<P><<<aggBlocks, bs, 0, stream>>>(bufA, csr, off, dinv, b_pol, polbuf, N);
  // conv_val (MFConv, fused to scalar per node)
  k_mf<<<aggBlocks, bs, 0, stream>>>(bufB, csr, off, Wl, bl, Wr, valn, N);

  int poolBlocks = (N + 255) / 256;
  k_pool<<<poolBlocks, bs, 0, stream>>>(polbuf, valn, batch, out, cntg, N, G);
  k_fin<<<(G * 32 + bs - 1) / bs, bs, 0, stream>>>(out, cntg, G);
}

// Round 2
// 365.458 us; speedup vs baseline: 1.6176x; 1.6176x over previous
//
#include <hip/hip_runtime.h>

#define F 64
#define P 32
#define MAXD 10

// ---------------- degree count ----------------
__global__ void k_count_deg(const int* __restrict__ dst, int* __restrict__ deg, int E) {
  int i = blockIdx.x * blockDim.x + threadIdx.x;
  int stride = gridDim.x * blockDim.x;
  for (int e = i; e < E; e += stride) atomicAdd(&deg[dst[e]], 1);
}

// ---------------- hierarchical scan: phase 1 — per-block sums (256 nodes/block) ----------------
__global__ void k_bsum(const int* __restrict__ deg, int* __restrict__ bsum, int N) {
  __shared__ int s[256];
  int t = threadIdx.x;
  int n = blockIdx.x * 256 + t;
  s[t] = (n < N) ? deg[n] : 0;
  __syncthreads();
  for (int o = 128; o > 0; o >>= 1) {
    if (t < o) s[t] += s[t + o];
    __syncthreads();
  }
  if (t == 0) bsum[blockIdx.x] = s[0];
}

// ---------------- phase 2 — single-block exclusive scan of block sums (B <= 1024) ----------------
__global__ void k_scan_bsum(int* __restrict__ bsum, int B) {
  __shared__ int s[1024];
  int t = threadIdx.x;
  int v = (t < B) ? bsum[t] : 0;
  s[t] = v;
  __syncthreads();
  for (int o = 1; o < 1024; o <<= 1) {
    int u = (t >= o) ? s[t - o] : 0;
    __syncthreads();
    s[t] += u;
    __syncthreads();
  }
  if (t < B) bsum[t] = s[t] - v;  // exclusive base per block
}

// ---------------- phase 3 — per-block local scan, write off/cur/dinv ----------------
__global__ void k_scan_fin(const int* __restrict__ deg, const int* __restrict__ bsum,
                           int* __restrict__ off, int* __restrict__ cur,
                           float* __restrict__ dinv, int N) {
  __shared__ int s[256];
  int t = threadIdx.x;
  int n = blockIdx.x * 256 + t;
  int v = (n < N) ? deg[n] : 0;
  s[t] = v;
  __syncthreads();
  for (int o = 1; o < 256; o <<= 1) {
    int u = (t >= o) ? s[t - o] : 0;
    __syncthreads();
    s[t] += u;
    __syncthreads();
  }
  if (n < N) {
    int ex = bsum[blockIdx.x] + s[t] - v;  // exclusive prefix
    off[n] = ex;
    cur[n] = ex;
    dinv[n] = rsqrtf((float)(v + 1));  // +1 self loop (GCN)
    if (n == N - 1) off[N] = ex + v;
  }
}

// ---------------- CSR fill: per dst node, list of src ----------------
__global__ void k_fill(const int* __restrict__ src, const int* __restrict__ dst,
                       int* __restrict__ cur, int* __restrict__ csr, int E) {
  int i = blockIdx.x * blockDim.x + threadIdx.x;
  int stride = gridDim.x * blockDim.x;
  for (int e = i; e < E; e += stride) {
    int d = dst[e];
    int pos = atomicAdd(&cur[d], 1);
    csr[pos] = src[e];
  }
}

// ---------------- GEMM: out[n,f] = dinv[n] * sum_k X[n,k] * W[k,f] ----------------
// wave per node (grid-stride), lane f holds column f of W in registers
template <int KOUT>
__global__ void k_gemm(const float* __restrict__ X, const float* __restrict__ W,
                       const float* __restrict__ dinv, float* __restrict__ out, int N) {
  int gtid = blockIdx.x * blockDim.x + threadIdx.x;
  int wave = gtid >> 6;
  int lane = threadIdx.x & 63;
  int nwaves = (gridDim.x * blockDim.x) >> 6;
  int f = lane & (KOUT - 1);
  float w[F];
#pragma unroll
  for (int k = 0; k < F; ++k) w[k] = W[k * KOUT + f];
  for (int n = wave; n < N; n += nwaves) {
    float xv = X[(size_t)n * F + lane];
    float acc = 0.f;
#pragma unroll
    for (int k = 0; k < F; ++k) acc += __shfl(xv, k, 64) * w[k];
    if (lane < KOUT) out[(size_t)n * KOUT + lane] = acc * dinv[n];
  }
}

// ---------------- GCN aggregation (vectorized): out[n] = dinv[n]*(sum_adj T[src] + T[n]) + b ----
// Wave split into NG groups of LPG lanes; each group loads one edge row as float4.
template <int KOUT>
__global__ void k_agg(const float* __restrict__ T, const int* __restrict__ csr,
                      const int* __restrict__ off, const float* __restrict__ dinv,
                      const float* __restrict__ bias, float* __restrict__ out, int N) {
  constexpr int LPG = KOUT / 4;  // lanes per group
  constexpr int NG = 64 / LPG;   // edges processed per serial step
  int wave = (blockIdx.x * blockDim.x + threadIdx.x) >> 6;
  int lane = threadIdx.x & 63;
  if (wave >= N) return;
  int n = wave;
  int e0 = off[n], e1 = off[n + 1];
  int g = lane / LPG;
  int l = lane % LPG;
  float4 acc = make_float4(0.f, 0.f, 0.f, 0.f);
  for (int e = e0; e < e1; e += 64) {
    int se = (e + lane < e1) ? csr[e + lane] : -1;
    int nj = (min(64, e1 - e) + NG - 1) / NG;
    for (int j = 0; j < nj; ++j) {
      int s = __shfl(se, j * NG + g, 64);
      if (s >= 0) {
        float4 v = *(const float4*)&T[(size_t)s * KOUT + l * 4];
        acc.x += v.x; acc.y += v.y; acc.z += v.z; acc.w += v.w;
      }
    }
  }
  // reduce across groups
#pragma unroll
  for (int o = LPG; o < 64; o <<= 1) {
    acc.x += __shfl_xor(acc.x, o, 64);
    acc.y += __shfl_xor(acc.y, o, 64);
    acc.z += __shfl_xor(acc.z, o, 64);
    acc.w += __shfl_xor(acc.w, o, 64);
  }
  if (g == 0) {
    float4 self = *(const float4*)&T[(size_t)n * KOUT + l * 4];
    float4 b4 = *(const float4*)&bias[l * 4];
    float dn = dinv[n];
    float4 r;
    r.x = (acc.x + self.x) * dn + b4.x;
    r.y = (acc.y + self.y) * dn + b4.y;
    r.z = (acc.z + self.z) * dn + b4.z;
    r.w = (acc.w + self.w) * dn + b4.w;
    *(float4*)&out[(size_t)n * KOUT + l * 4] = r;
  }
}

// ---------------- MFConv fused (vectorized): val[n] = <sum_adj H, Wl[dc]> + <H[n], Wr[dc]> + bl[dc]
__global__ void k_mf(const float* __restrict__ H, const int* __restrict__ csr,
                     const int* __restrict__ off, const float* __restrict__ Wl,
                     const float* __restrict__ bl, const float* __restrict__ Wr,
                     float* __restrict__ val, int N) {
  constexpr int LPG = 16, NG = 4;
  int wave = (blockIdx.x * blockDim.x + threadIdx.x) >> 6;
  int lane = threadIdx.x & 63;
  if (wave >= N) return;
  int n = wave;
  int e0 = off[n], e1 = off[n + 1];
  int g = lane >> 4;
  int l = lane & 15;
  float4 acc = make_float4(0.f, 0.f, 0.f, 0.f);
  for (int e = e0; e < e1; e += 64) {
    int se = (e + lane < e1) ? csr[e + lane] : -1;
    int nj = (min(64, e1 - e) + NG - 1) / NG;
    for (int j = 0; j < nj; ++j) {
      int s = __shfl(se, j * NG + g, 64);
      if (s >= 0) {
        float4 v = *(const float4*)&H[(size_t)s * F + l * 4];
        acc.x += v.x; acc.y += v.y; acc.z += v.z; acc.w += v.w;
      }
    }
  }
#pragma unroll
  for (int o = 16; o < 64; o <<= 1) {
    acc.x += __shfl_xor(acc.x, o, 64);
    acc.y += __shfl_xor(acc.y, o, 64);
    acc.z += __shfl_xor(acc.z, o, 64);
    acc.w += __shfl_xor(acc.w, o, 64);
  }
  int dc = min(e1 - e0, MAXD);
  float4 wl = *(const float4*)&Wl[dc * F + l * 4];
  float4 wr = *(const float4*)&Wr[dc * F + l * 4];
  float4 hn = *(const float4*)&H[(size_t)n * F + l * 4];
  float part = acc.x * wl.x + acc.y * wl.y + acc.z * wl.z + acc.w * wl.w
             + hn.x * wr.x + hn.y * wr.y + hn.z * wr.z + hn.w * wr.w;
#pragma unroll
  for (int o = 1; o < 16; o <<= 1) part += __shfl_xor(part, o, 64);
  if (lane == 0) val[n] = part + bl[dc];
}

// ---------------- pooling: batch is SORTED -> per-block LDS accumulate, flush touched graphs ----
__global__ void k_pool(const float* __restrict__ pol, const float* __restrict__ val,
                       const int* __restrict__ batch, float* __restrict__ out,
                       float* __restrict__ cntg, int N, int G) {
  __shared__ float pol_l[64 * 32];
  __shared__ float val_l[64];
  __shared__ float cnt_l[64];
  int t = threadIdx.x;
  for (int i = t; i < 64 * 32; i += 256) pol_l[i] = 0.f;
  if (t < 64) { val_l[t] = 0.f; cnt_l[t] = 0.f; }
  __syncthreads();
  int base = blockIdx.x * 256;
  int p = t & 31, sub = t >> 5;
  for (int i = sub; i < 256; i += 8) {
    int n = base + i;
    if (n >= N) break;
    int g = batch[n];
    atomicAdd(&pol_l[g * 32 + p], pol[(size_t)n * 32 + p]);
    if (p == 0) {
      atomicAdd(&val_l[g], val[n]);
      atomicAdd(&cnt_l[g], 1.f);
    }
  }
  __syncthreads();
  int last = min(base + 256, N) - 1;
  if (last < base) return;
  int gmin = batch[base], gmax = batch[last];
  int ng = gmax - gmin + 1;
  for (int idx = t; idx < ng * 32; idx += 256) {
    int g = gmin + (idx >> 5), pp = idx & 31;
    atomicAdd(&out[g * 32 + pp], pol_l[g * 32 + pp]);
    if (pp == 0) {
      atomicAdd(&out[(size_t)G * 32 + g], val_l[g]);
      atomicAdd(&cntg[g], cnt_l[g]);
    }
  }
}

// ---------------- finalize: mean for policy ----------------
__global__ void k_fin(float* __restrict__ out, const float* __restrict__ cntg, int G) {
  int i = blockIdx.x * blockDim.x + threadIdx.x;
  if (i < G * 32) out[i] /= fmaxf(cntg[i >> 5], 1.0f);
}

extern "C" void kernel_launch(void* const* d_in, const int* in_sizes, int n_in,
                              void* d_out, int out_size, void* d_ws, size_t ws_size,
                              hipStream_t stream) {
  const float* x = (const float*)d_in[0];
  const int* ei = (const int*)d_in[1];
  const int* batch = (const int*)d_in[2];
  const float* W_in = (const float*)d_in[3];
  const float* b_in = (const float*)d_in[4];
  const float* W1 = (const float*)d_in[5];
  const float* b1 = (const float*)d_in[6];
  const float* Wl = (const float*)d_in[7];
  const float* bl = (const float*)d_in[8];
  const float* Wr = (const float*)d_in[9];
  const float* W_pol = (const float*)d_in[10];
  const float* b_pol = (const float*)d_in[11];
  float* out = (float*)d_out;

  const int N = in_sizes[0] / F;
  const int E = in_sizes[1] / 2;
  const int G = out_size / (P + 1);
  const int* esrc = ei;
  const int* edst = ei + E;

  char* ws = (char*)d_ws;
  size_t o = 0;
  auto alloc = [&](size_t bytes) {
    char* r = ws + o;
    o = (o + bytes + 255) & ~(size_t)255;
    return r;
  };
  int* deg = (int*)alloc((size_t)N * 4);
  int* off = (int*)alloc((size_t)(N + 1) * 4);
  int* cur = (int*)alloc((size_t)N * 4);
  float* dinv = (float*)alloc((size_t)N * 4);
  int* csr = (int*)alloc((size_t)E * 4);
  float* cntg = (float*)alloc((size_t)G * 4);
  float* valn = (float*)alloc((size_t)N * 4);
  int* bsum = (int*)alloc(1024 * 4);
  float* bufA = (float*)alloc((size_t)N * F * 4);
  float* bufB = (float*)alloc((size_t)N * F * 4);
  float* polbuf = bufA + (size_t)N * P;  // alias upper half of bufA (gemm<P> out lives in lower half)
  (void)ws_size; (void)n_in;

  hipMemsetAsync(deg, 0, (size_t)N * 4, stream);
  hipMemsetAsync(cntg, 0, (size_t)G * 4, stream);
  hipMemsetAsync(d_out, 0, (size_t)out_size * 4, stream);

  const int bs = 256;
  const int B = (N + 255) / 256;  // scan blocks (196 for N=50000, must be <= 1024)
  k_count_deg<<<1024, bs, 0, stream>>>(edst, deg, E);
  k_bsum<<<B, bs, 0, stream>>>(deg, bsum, N);
  k_scan_bsum<<<1, 1024, 0, stream>>>(bsum, B);
  k_scan_fin<<<B, bs, 0, stream>>>(deg, bsum, off, cur, dinv, N);
  k_fill<<<1024, bs, 0, stream>>>(esrc, edst, cur, csr, E);

  int aggBlocks = (N * 64 + bs - 1) / bs;  // wave per node, 4 waves/block

  // conv_in: t1' = dinv * (x @ W_in); h1 = dinv*(sum t1' + self) + b_in
  k_gemm<F><<<2048, bs, 0, stream>>>(x, W_in, dinv, bufA, N);
  k_agg<F><<<aggBlocks, bs, 0, stream>>>(bufA, csr, off, dinv, b_in, bufB, N);
  // conv_1
  k_gemm<F><<<2048, bs, 0, stream>>>(bufB, W1, dinv, bufA, N);
  k_agg<F><<<aggBlocks, bs, 0, stream>>>(bufA, csr, off, dinv, b1, bufB, N);
  // conv_policy (GEMM first: scatter only 32 feats)
  k_gemm<P><<<2048, bs, 0, stream>>>(bufB, W_pol, dinv, bufA, N);
  k_agg<P><<<aggBlocks, bs, 0, stream>>>(bufA, csr, off, dinv, b_pol, polbuf, N);
  // conv_val (MFConv, fused to scalar per node)
  k_mf<<<aggBlocks, bs, 0, stream>>>(bufB, csr, off, Wl, bl, Wr, valn, N);

  int poolBlocks = (N + 255) / 256;
  k_pool<<<poolBlocks, bs, 0, stream>>>(polbuf, valn, batch, out, cntg, N, G);
  k_fin<<<(G * 32 + bs - 1) / bs, bs, 0, stream>>>(out, cntg, G);
}